// Round 1
// baseline (5246.688 us; speedup 1.0000x reference)
//
#include <hip/hip_runtime.h>
#include <math.h>

// ---------------------------------------------------------------------------
// ModelSpectral: hierarchical SAGEConv unpooling + MLP tail + QR(524288x2).
//
// Scheme: all conv outputs are stored PRE-tanh; every consumer applies tanhf.
// Per level l (5..0):
//   gather:   Q[i] = P[inv[i]]                       (pre-tanh copy)
//   deg:      deg[dst]+=1 ; invdeg = 1/max(deg,1)
//   conv:     agg[dst] += tanh(x[src])  (atomics)
//             out[i] = (agg[i]*invdeg[i])@Wl + tanh(x[i])@Wr + b   (in place)
// Tail: fused MLP (tanh on input) -> y[n,2] in d_out, + double-precision
// sums (||a||^2, a.b, ||b||^2) for LAPACK-convention Householder QR.
// ---------------------------------------------------------------------------

static inline int imin(int a, int b) { return a < b ? a : b; }

__global__ void coarse_kernel(float* __restrict__ out, const float* __restrict__ Wl,
                              const float* __restrict__ Wr, const float* __restrict__ b) {
    int t = threadIdx.x;
    if (t < 64) {
        int i = t >> 5, c = t & 31;
        // x = eye(2); edges [[0,1],[1,0]]: agg[i] = x[1-i], deg=1
        out[i * 32 + c] = Wl[(1 ^ i) * 32 + c] + Wr[i * 32 + c] + b[c];  // pre-tanh
    }
}

__global__ void gather_kernel(float* __restrict__ out, const float* __restrict__ in,
                              const int* __restrict__ inv, int n) {
    int total = n * 32;
    int stride = gridDim.x * blockDim.x;
    for (int idx = blockIdx.x * blockDim.x + threadIdx.x; idx < total; idx += stride) {
        int i = idx >> 5, j = idx & 31;
        out[idx] = in[inv[i] * 32 + j];
    }
}

__global__ void deg_kernel(float* __restrict__ deg, const int* __restrict__ dst, int E) {
    int stride = gridDim.x * blockDim.x;
    for (int e = blockIdx.x * blockDim.x + threadIdx.x; e < E; e += stride)
        unsafeAtomicAdd(&deg[dst[e]], 1.0f);
}

__global__ void invdeg_kernel(float* __restrict__ deg, int n) {
    int stride = gridDim.x * blockDim.x;
    for (int i = blockIdx.x * blockDim.x + threadIdx.x; i < n; i += stride)
        deg[i] = 1.0f / fmaxf(deg[i], 1.0f);
}

// agg[dst] += tanh(x[src]); 32 lanes per edge (lane j = feature j)
__global__ void scatter_kernel(float* __restrict__ agg, const float* __restrict__ x,
                               const int* __restrict__ edges, int E) {
    const int* __restrict__ src = edges;
    const int* __restrict__ dst = edges + E;
    int total = E * 32;
    int stride = gridDim.x * blockDim.x;
    for (int idx = blockIdx.x * blockDim.x + threadIdx.x; idx < total; idx += stride) {
        int e = idx >> 5, j = idx & 31;
        float v = tanhf(x[src[e] * 32 + j]);
        unsafeAtomicAdd(&agg[dst[e] * 32 + j], v);
    }
}

// in place: agg[i] <- (agg[i]*invdeg[i])@Wl + tanh(x[i])@Wr + b   (pre-tanh out)
__global__ void dense_kernel(float* __restrict__ agg, const float* __restrict__ x,
                             const float* __restrict__ invdeg,
                             const float* __restrict__ Wl, const float* __restrict__ Wr,
                             const float* __restrict__ b, int n) {
    __shared__ float sWl[1024], sWr[1024], sb[32];
    for (int t = threadIdx.x; t < 1024; t += blockDim.x) { sWl[t] = Wl[t]; sWr[t] = Wr[t]; }
    if (threadIdx.x < 32) sb[threadIdx.x] = b[threadIdx.x];
    __syncthreads();
    int row = blockIdx.x * 8 + (threadIdx.x >> 5);
    int c = threadIdx.x & 31;
    if (row >= n) return;
    float av = agg[row * 32 + c] * invdeg[row];
    float xv = tanhf(x[row * 32 + c]);
    float acc = sb[c];
#pragma unroll
    for (int k = 0; k < 32; ++k) {
        float a = __shfl(av, k, 32);
        float t = __shfl(xv, k, 32);
        acc += a * sWl[k * 32 + c] + t * sWr[k * 32 + c];
    }
    agg[row * 32 + c] = acc;
}

// fused MLP tail: y = tanh(tanh(tanh(tanh(x)W1+b1)W2+b2)W3+b3)Wf+bf
// also accumulate double sums: saa=sum(y0^2), sab=sum(y0*y1), sbb=sum(y1^2)
__global__ void mlp_kernel(float* __restrict__ y, const float* __restrict__ x,
                           const float* __restrict__ W1, const float* __restrict__ b1,
                           const float* __restrict__ W2, const float* __restrict__ b2,
                           const float* __restrict__ W3, const float* __restrict__ b3,
                           const float* __restrict__ Wf, const float* __restrict__ bf,
                           double* __restrict__ sums, int n) {
    __shared__ float sW1[512], sb1[16], sW2[512], sb2[32], sW3[1024], sb3[32], sWf[64], sbf[2];
    for (int t = threadIdx.x; t < 512; t += blockDim.x) { sW1[t] = W1[t]; sW2[t] = W2[t]; }
    for (int t = threadIdx.x; t < 1024; t += blockDim.x) sW3[t] = W3[t];
    if (threadIdx.x < 64) sWf[threadIdx.x] = Wf[threadIdx.x];
    if (threadIdx.x < 16) sb1[threadIdx.x] = b1[threadIdx.x];
    if (threadIdx.x < 32) { sb2[threadIdx.x] = b2[threadIdx.x]; sb3[threadIdx.x] = b3[threadIdx.x]; }
    if (threadIdx.x < 2) sbf[threadIdx.x] = bf[threadIdx.x];
    __syncthreads();

    double la = 0.0, lab = 0.0, lb = 0.0;
    int stride = gridDim.x * blockDim.x;
    for (int row = blockIdx.x * blockDim.x + threadIdx.x; row < n; row += stride) {
        float h1[16];
#pragma unroll
        for (int c = 0; c < 16; ++c) h1[c] = sb1[c];
        for (int k = 0; k < 32; ++k) {
            float t = tanhf(x[row * 32 + k]);
#pragma unroll
            for (int c = 0; c < 16; ++c) h1[c] += t * sW1[k * 16 + c];
        }
        float h2[32];
#pragma unroll
        for (int c = 0; c < 32; ++c) h2[c] = sb2[c];
        for (int k = 0; k < 16; ++k) {
            float t = tanhf(h1[k]);
#pragma unroll
            for (int c = 0; c < 32; ++c) h2[c] += t * sW2[k * 32 + c];
        }
        float h3[32];
#pragma unroll
        for (int c = 0; c < 32; ++c) h3[c] = sb3[c];
        for (int k = 0; k < 32; ++k) {
            float t = tanhf(h2[k]);
#pragma unroll
            for (int c = 0; c < 32; ++c) h3[c] += t * sW3[k * 32 + c];
        }
        float y0 = sbf[0], y1 = sbf[1];
        for (int k = 0; k < 32; ++k) {
            float t = tanhf(h3[k]);
            y0 += t * sWf[k * 2];
            y1 += t * sWf[k * 2 + 1];
        }
        y[row * 2] = y0;
        y[row * 2 + 1] = y1;
        la += (double)y0 * (double)y0;
        lab += (double)y0 * (double)y1;
        lb += (double)y1 * (double)y1;
    }
    // wave (64) reduce, then block reduce, then one atomic per block
#pragma unroll
    for (int off = 32; off > 0; off >>= 1) {
        la += __shfl_down(la, off);
        lab += __shfl_down(lab, off);
        lb += __shfl_down(lb, off);
    }
    __shared__ double red[4][3];
    int wid = threadIdx.x >> 6;
    if ((threadIdx.x & 63) == 0) { red[wid][0] = la; red[wid][1] = lab; red[wid][2] = lb; }
    __syncthreads();
    if (threadIdx.x == 0) {
        double ta = 0, tb = 0, tc = 0;
        int nw = (blockDim.x + 63) / 64;
        for (int w = 0; w < nw; ++w) { ta += red[w][0]; tb += red[w][1]; tc += red[w][2]; }
        unsafeAtomicAdd(&sums[0], ta);
        unsafeAtomicAdd(&sums[1], tb);
        unsafeAtomicAdd(&sums[2], tc);
    }
}

// LAPACK (geqrf/orgqr) Householder sign convention for 2-column QR.
__global__ void qr_scalar_kernel(float* __restrict__ scal, const double* __restrict__ sums,
                                 const float* __restrict__ y) {
    double saa = sums[0], sab = sums[1], sbb = sums[2];
    double a0 = (double)y[0], b0 = (double)y[1];
    double a1 = (double)y[2], b1v = (double)y[3];
    double na = sqrt(saa);
    double beta1 = (a0 >= 0.0) ? -na : na;       // beta = -sign(alpha)*||a||
    double R12 = sab / beta1;                    // (H1 b)[0] = q1.b
    double v2 = sbb - R12 * R12;                 // ||b - R12 q1||^2
    if (v2 < 0.0) v2 = 0.0;
    double nb = sqrt(v2);
    double denom = a0 - beta1;                   // nonzero: a0 + sign(a0)||a||
    double tau1 = (beta1 - a0) / beta1;
    double u1b = b0 + (sab - a0 * b0) / denom;   // v1 . b  (v1[0]=1)
    double y1h = b1v - tau1 * u1b * (a1 / denom);// (H1 b)[1] -> pivot of reflector 2
    double beta2 = (y1h >= 0.0) ? -nb : nb;
    scal[0] = (float)(1.0 / beta1);
    scal[1] = (float)R12;
    scal[2] = (float)(1.0 / beta2);
}

__global__ void q_kernel(float* __restrict__ y, const float* __restrict__ scal, int n) {
    float invb1 = scal[0], R12 = scal[1], invb2 = scal[2];
    int stride = gridDim.x * blockDim.x;
    float2* p = (float2*)y;
    for (int i = blockIdx.x * blockDim.x + threadIdx.x; i < n; i += stride) {
        float2 v = p[i];
        float qa = v.x * invb1;
        float qb = (v.y - R12 * qa) * invb2;
        p[i] = make_float2(qa, qb);
    }
}

extern "C" void kernel_launch(void* const* d_in, const int* in_sizes, int n_in,
                              void* d_out, int out_size, void* d_ws, size_t ws_size,
                              hipStream_t stream) {
    const int* edges[6];
    const int* inv[6];
    int nl[6], El[6];
    for (int l = 0; l < 6; ++l) {
        edges[l] = (const int*)d_in[2 * l];
        inv[l] = (const int*)d_in[2 * l + 1];
        El[l] = in_sizes[2 * l] / 2;
        nl[l] = in_sizes[2 * l + 1];
    }
    const float* Wc_l = (const float*)d_in[13];
    const float* Wc_r = (const float*)d_in[14];
    const float* bc = (const float*)d_in[15];
    const float* Wp_l[2] = {(const float*)d_in[16], (const float*)d_in[19]};
    const float* Wp_r[2] = {(const float*)d_in[17], (const float*)d_in[20]};
    const float* bp[2] = {(const float*)d_in[18], (const float*)d_in[21]};
    const float* W1 = (const float*)d_in[22];
    const float* b1 = (const float*)d_in[23];
    const float* W2 = (const float*)d_in[24];
    const float* b2 = (const float*)d_in[25];
    const float* W3 = (const float*)d_in[26];
    const float* b3 = (const float*)d_in[27];
    const float* Wf = (const float*)d_in[28];
    const float* bf = (const float*)d_in[29];

    // workspace carve: bufA 64MB | bufB 64MB | deg 2MB | sums 24B | scal 12B
    char* ws = (char*)d_ws;
    float* bufA = (float*)ws;
    float* bufB = (float*)(ws + 67108864);
    float* deg = (float*)(ws + 134217728);
    double* sums = (double*)(ws + 136314880);
    float* scal = (float*)(ws + 136315008);

    float* P = bufA;  // holds previous-level pre-tanh result
    float* Q = bufB;
    coarse_kernel<<<1, 64, 0, stream>>>(P, Wc_l, Wc_r, bc);

    for (int l = 5; l >= 0; --l) {
        int n = nl[l], E = El[l];
        gather_kernel<<<imin((n * 32 + 255) / 256, 65536), 256, 0, stream>>>(Q, P, inv[l], n);
        hipMemsetAsync(deg, 0, (size_t)n * sizeof(float), stream);
        deg_kernel<<<imin((E + 255) / 256, 32768), 256, 0, stream>>>(deg, edges[l] + E, E);
        invdeg_kernel<<<imin((n + 255) / 256, 8192), 256, 0, stream>>>(deg, n);
        // conv1: agg in P, x in Q
        hipMemsetAsync(P, 0, (size_t)n * 32 * sizeof(float), stream);
        scatter_kernel<<<imin((E * 32 + 255) / 256, 65536), 256, 0, stream>>>(P, Q, edges[l], E);
        dense_kernel<<<(n + 7) / 8, 256, 0, stream>>>(P, Q, deg, Wp_l[0], Wp_r[0], bp[0], n);
        // conv2: agg in Q, x in P
        hipMemsetAsync(Q, 0, (size_t)n * 32 * sizeof(float), stream);
        scatter_kernel<<<imin((E * 32 + 255) / 256, 65536), 256, 0, stream>>>(Q, P, edges[l], E);
        dense_kernel<<<(n + 7) / 8, 256, 0, stream>>>(Q, P, deg, Wp_l[1], Wp_r[1], bp[1], n);
        float* t = P; P = Q; Q = t;
    }

    hipMemsetAsync(sums, 0, 3 * sizeof(double), stream);
    mlp_kernel<<<2048, 256, 0, stream>>>((float*)d_out, P, W1, b1, W2, b2, W3, b3, Wf, bf,
                                         sums, nl[0]);
    qr_scalar_kernel<<<1, 1, 0, stream>>>(scal, sums, (const float*)d_out);
    q_kernel<<<imin((nl[0] + 255) / 256, 4096), 256, 0, stream>>>((float*)d_out, scal, nl[0]);
}